// Round 5
// baseline (597.932 us; speedup 1.0000x reference)
//
#include <hip/hip_runtime.h>

// ---------------- constants ----------------
#define BATCH   2
#define SEQLEN  1024
#define DMODEL  512
#define DSTATE  32
#define DINNER  1024
#define MROWS   (BATCH*SEQLEN)          // 2048
#define NPROJ   (2*DINNER + 2*DINNER*DSTATE)  // 67584

typedef short bf16x8 __attribute__((ext_vector_type(8)));
typedef float f32x4  __attribute__((ext_vector_type(4)));

__device__ __forceinline__ unsigned short f2bf(float f) {
    union { float f; unsigned u; } c; c.f = f;
    unsigned u = c.u;
    u += 0x7fffu + ((u >> 16) & 1u);   // RTNE
    return (unsigned short)(u >> 16);
}
__device__ __forceinline__ float bf2f(unsigned short h) {
    union { unsigned u; float f; } c; c.u = ((unsigned)h) << 16;
    return c.f;
}

// ---------------- cast fp32 -> bf16 (weights concat + x + Wout) ----------------
__global__ void cast_all(const float4* __restrict__ Wx, const float4* __restrict__ Wdt,
                         const float4* __restrict__ WB, const float4* __restrict__ WC,
                         const float4* __restrict__ x,  const float4* __restrict__ Wout,
                         unsigned short* __restrict__ Wbf,
                         unsigned short* __restrict__ Xbf,
                         unsigned short* __restrict__ Woutbf) {
    const long nWx = 131072, nWdt = 131072, nWB = 4194304, nWC = 4194304;
    const long nWall = nWx + nWdt + nWB + nWC;      // 8650752
    const long nX = 262144, nWo = 131072;
    const long total = nWall + nX + nWo;            // 9043968
    for (long u = (long)blockIdx.x * blockDim.x + threadIdx.x; u < total;
         u += (long)gridDim.x * blockDim.x) {
        float4 v; unsigned short* dst;
        if (u < nWall) {
            if (u < nWx)             v = Wx[u];
            else if (u < nWx+nWdt)   v = Wdt[u - nWx];
            else if (u < nWx+nWdt+nWB) v = WB[u - nWx - nWdt];
            else                     v = WC[u - nWx - nWdt - nWB];
            dst = Wbf + u*4;
        } else if (u < nWall + nX) {
            v = x[u - nWall];       dst = Xbf + (u - nWall)*4;
        } else {
            v = Wout[u - nWall - nX]; dst = Woutbf + (u - nWall - nX)*4;
        }
        ushort4 o; o.x = f2bf(v.x); o.y = f2bf(v.y); o.z = f2bf(v.z); o.w = f2bf(v.w);
        *(ushort4*)dst = o;
    }
}

// ---------------- bf16 MFMA GEMM: C[rows,N] = A[rows,K] * Bw[N,K]^T ----------------
// 128x128 tile, BK=32, 4 waves (2x2). XCD band swizzle; 3-deep pipeline with
// counted vmcnt(8); LDS bank-conflict-free via pre-swizzled GLOBAL source +
// same-involution swizzled ds_read (linear LDS dest for global_load_lds).
// Swizzle: 16B slot' = slot ^ ((row>>1)&3)  (rows 0..7 x fixed h16 -> all 32 banks).
template<int EPI>
__global__ __launch_bounds__(256)
void gemm_bt(const unsigned short* __restrict__ A, const unsigned short* __restrict__ Bw,
             int K, int N, int t0, int Tchunk,
             float* __restrict__ xin, float* __restrict__ dlt,
             unsigned short* __restrict__ Bout, unsigned short* __restrict__ Cout,
             const float* __restrict__ bdt, float* __restrict__ outf) {
    __shared__ unsigned short Asm[3][128*32];
    __shared__ unsigned short Bsm[3][128*32];
    const int tid  = threadIdx.x;
    const int w    = tid >> 6;
    const int lane = tid & 63;
    const int wm   = w >> 1, wn = w & 1;

    // ---- XCD band swizzle ----
    const int nx = gridDim.x, ny = gridDim.y;
    int ntile, rtile;
    if ((nx & 7) == 0) {
        const int lin = blockIdx.x + nx * blockIdx.y;
        const int xcd = lin & 7;
        const int sl  = lin >> 3;
        ntile = xcd * (nx >> 3) + sl / ny;
        rtile = sl % ny;
    } else {
        ntile = blockIdx.x; rtile = blockIdx.y;
    }

    const int rr0  = rtile * 128;                 // chunk-local row base of tile
    const int bb   = (rr0 >= Tchunk) ? 1 : 0;
    const int grow0 = bb * SEQLEN + t0 + (rr0 - bb * Tchunk);  // global row base
    const int n0   = ntile * 128;

    f32x4 acc[4][4] = {};

    const unsigned short* Ag = A  + (size_t)grow0 * K;
    const unsigned short* Bg = Bw + (size_t)n0 * K;

    const int c0 = w*64 + lane;       // LDS chunk ids (16B units)
    const int c1 = c0 + 256;
    const int r   = lane & 15;
    const int h16 = lane >> 4;

    // pre-swizzled global source offsets (shorts), add k0 per iteration
    const int rowc0 = c0 >> 2, rowc1 = c1 >> 2;
    const int subc0 = (c0 & 3) ^ ((c0 >> 3) & 3);
    const int subc1 = (c1 & 3) ^ ((c1 >> 3) & 3);
    const size_t srcA0 = (size_t)rowc0 * K + subc0 * 8;
    const size_t srcA1 = (size_t)rowc1 * K + subc1 * 8;

    const int nt = K >> 5;            // K/32 iterations

    #define STAGE(k0_, buf_)                                                              \
        do {                                                                              \
            __builtin_amdgcn_global_load_lds(                                             \
                (const __attribute__((address_space(1))) void*)(Ag + srcA0 + (k0_)),      \
                (__attribute__((address_space(3))) void*)(&Asm[(buf_)][w*512]), 16, 0, 0);\
            __builtin_amdgcn_global_load_lds(                                             \
                (const __attribute__((address_space(1))) void*)(Ag + srcA1 + (k0_)),      \
                (__attribute__((address_space(3))) void*)(&Asm[(buf_)][2048 + w*512]), 16, 0, 0); \
            __builtin_amdgcn_global_load_lds(                                             \
                (const __attribute__((address_space(1))) void*)(Bg + srcA0 + (k0_)),      \
                (__attribute__((address_space(3))) void*)(&Bsm[(buf_)][w*512]), 16, 0, 0);\
            __builtin_amdgcn_global_load_lds(                                             \
                (const __attribute__((address_space(1))) void*)(Bg + srcA1 + (k0_)),      \
                (__attribute__((address_space(3))) void*)(&Bsm[(buf_)][2048 + w*512]), 16, 0, 0); \
        } while (0)

    #define COMPUTE(buf_)                                                                 \
        do {                                                                              \
            bf16x8 af[4], bfr[4];                                                         \
            _Pragma("unroll")                                                             \
            for (int i = 0; i < 4; i++) {                                                 \
                const int Ra = wm*64 + i*16 + r;                                          \
                const int Rb = wn*64 + i*16 + r;                                          \
                af[i]  = *(const bf16x8*)(&Asm[(buf_)][Ra*32 + (h16 ^ ((Ra>>1)&3))*8]);   \
                bfr[i] = *(const bf16x8*)(&Bsm[(buf_)][Rb*32 + (h16 ^ ((Rb>>1)&3))*8]);   \
            }                                                                             \
            _Pragma("unroll")                                                             \
            for (int i = 0; i < 4; i++)                                                   \
                _Pragma("unroll")                                                         \
                for (int j = 0; j < 4; j++)                                               \
                    acc[i][j] = __builtin_amdgcn_mfma_f32_16x16x32_bf16(af[i], bfr[j], acc[i][j], 0, 0, 0); \
        } while (0)

    STAGE(0, 0);
    STAGE(32, 1);
    for (int it = 0; it < nt; ++it) {
        if (it + 2 < nt) {
            STAGE((it + 2) * 32, (it + 2) % 3);
            asm volatile("s_waitcnt vmcnt(8)" ::: "memory");   // tiles it+1, it+2 in flight
        } else if (it + 1 < nt) {
            asm volatile("s_waitcnt vmcnt(4)" ::: "memory");   // tile it+1 in flight
        } else {
            asm volatile("s_waitcnt vmcnt(0)" ::: "memory");
        }
        __builtin_amdgcn_s_barrier();      // all waves' tile-it loads landed
        COMPUTE(it % 3);
        asm volatile("" ::: "memory");
        __builtin_amdgcn_s_barrier();      // protect buf (it%3) before re-stage
        asm volatile("" ::: "memory");
    }

    #undef STAGE
    #undef COMPUTE

    // epilogue: C/D layout col=lane&15, row=(lane>>4)*4+reg
    const int q = lane >> 4;
    #pragma unroll
    for (int i = 0; i < 4; i++) {
        #pragma unroll
        for (int j = 0; j < 4; j++) {
            const int lr0  = wm*64 + i*16 + q*4;   // local row within tile
            const int ncol = n0 + wn*64 + j*16 + r;
            #pragma unroll
            for (int t = 0; t < 4; t++) {
                const int lr = lr0 + t;
                const int mm = grow0 + lr;          // global row
                const int cr = rr0 + lr;            // chunk-local row
                const float v = acc[i][j][t];
                if (EPI == 0) {
                    if (ncol < 1024) {
                        xin[(size_t)mm*1024 + ncol] = v;
                    } else if (ncol < 2048) {
                        float z = v + bdt[ncol - 1024];
                        dlt[(size_t)mm*1024 + (ncol - 1024)] = (z > 20.f) ? z : log1pf(__expf(z));
                    } else if (ncol < 34816) {
                        Bout[(size_t)cr*32768 + (ncol - 2048)] = f2bf(v);
                    } else {
                        Cout[(size_t)cr*32768 + (ncol - 34816)] = f2bf(v);
                    }
                } else {
                    outf[(size_t)mm*N + ncol] = v;
                }
            }
        }
    }
}

// ================= segmented scan =================
// SC1: per (b,e) group and segment: local scan from h=0, record h_loc and
//      a_prod (32-dim each). grid: (256, SEG) blocks x 256 thr.
__global__ __launch_bounds__(256)
void scan_seg1(const float* __restrict__ dlt, const float* __restrict__ xin,
               const unsigned short* __restrict__ Bbf,
               const float* __restrict__ A_log,
               float* __restrict__ sc_h, float* __restrict__ sc_a,
               int t0, int Tchunk, int SEG, int Tg) {
    const int tid = threadIdx.x;
    const int g = tid >> 5;
    const int s = tid & 31;
    const int G = blockIdx.x * 8 + g;        // 0..2047 (b,e)
    const int seg = blockIdx.y;
    const int b = G >> 10, e = G & 1023;

    const float Aes = -__expf(A_log[e*32 + s]);
    float h = 0.f, ap = 1.f;

    const int lt0 = seg * Tg;                      // chunk-local start
    const size_t rowBC = (size_t)b*Tchunk*32768 + (size_t)e*32 + s;
    const size_t rowDX = (size_t)b*1024*1024 + e;

    const int CH = 8;
    float db[CH], xb[CH], bv[CH];
    #pragma unroll
    for (int j = 0; j < CH; j++) {
        db[j] = dlt[rowDX + (size_t)(t0 + lt0 + j)*1024];
        xb[j] = xin[rowDX + (size_t)(t0 + lt0 + j)*1024];
        bv[j] = bf2f(Bbf[rowBC + (size_t)(lt0 + j)*32768]);
    }
    for (int tc = 0; tc < Tg; tc += CH) {
        float ndb[CH], nxb[CH], nbv[CH];
        const bool more = (tc + CH) < Tg;
        if (more) {
            #pragma unroll
            for (int j = 0; j < CH; j++) {
                const size_t lt2 = lt0 + tc + CH + j;
                ndb[j] = dlt[rowDX + (t0 + lt2)*1024];
                nxb[j] = xin[rowDX + (t0 + lt2)*1024];
                nbv[j] = bf2f(Bbf[rowBC + lt2*32768]);
            }
        }
        #pragma unroll
        for (int j = 0; j < CH; j++) {
            const float a = __expf(db[j] * Aes);
            h = a*h + bv[j]*xb[j];
            ap *= a;
        }
        if (more) {
            #pragma unroll
            for (int j = 0; j < CH; j++) { db[j]=ndb[j]; xb[j]=nxb[j]; bv[j]=nbv[j]; }
        }
    }
    sc_h[((size_t)G*SEG + seg)*32 + s] = h;
    sc_a[((size_t)G*SEG + seg)*32 + s] = ap;
}

// SC2: compose segment boundaries sequentially (SEG steps). 65536 threads.
__global__ __launch_bounds__(256)
void scan_seg2(const float* __restrict__ sc_h, const float* __restrict__ sc_a,
               float* __restrict__ sc_hin, float* __restrict__ hbuf,
               int SEG, int first) {
    const int idx = blockIdx.x * 256 + threadIdx.x;   // 0..65535 = G*32+s
    float h = first ? 0.f : hbuf[idx];
    const int G = idx >> 5, s = idx & 31;
    for (int seg = 0; seg < SEG; seg++) {
        const size_t o = ((size_t)G*SEG + seg)*32 + s;
        sc_hin[o] = h;
        h = sc_h[o] + sc_a[o]*h;
    }
    hbuf[idx] = h;
}

// SC3: re-scan each segment with correct h_in; emit y (SiLU) as bf16.
__global__ __launch_bounds__(256)
void scan_seg3(const float* __restrict__ dlt, const float* __restrict__ xin,
               const unsigned short* __restrict__ Bbf, const unsigned short* __restrict__ Cbf,
               const float* __restrict__ A_log, const float* __restrict__ sc_hin,
               unsigned short* __restrict__ Ybf,
               int t0, int Tchunk, int SEG, int Tg) {
    const int tid = threadIdx.x;
    const int g = tid >> 5;
    const int s = tid & 31;
    const int G = blockIdx.x * 8 + g;
    const int seg = blockIdx.y;
    const int b = G >> 10, e = G & 1023;

    const float Aes = -__expf(A_log[e*32 + s]);
    float h = sc_hin[((size_t)G*SEG + seg)*32 + s];

    const int lt0 = seg * Tg;
    const size_t rowBC = (size_t)b*Tchunk*32768 + (size_t)e*32 + s;
    const size_t rowDX = (size_t)b*1024*1024 + e;

    const int CH = 8;
    float db[CH], xb[CH], bv[CH], cv[CH];
    #pragma unroll
    for (int j = 0; j < CH; j++) {
        db[j] = dlt[rowDX + (size_t)(t0 + lt0 + j)*1024];
        xb[j] = xin[rowDX + (size_t)(t0 + lt0 + j)*1024];
        bv[j] = bf2f(Bbf[rowBC + (size_t)(lt0 + j)*32768]);
        cv[j] = bf2f(Cbf[rowBC + (size_t)(lt0 + j)*32768]);
    }
    for (int tc = 0; tc < Tg; tc += CH) {
        float ndb[CH], nxb[CH], nbv[CH], ncv[CH];
        const bool more = (tc + CH) < Tg;
        if (more) {
            #pragma unroll
            for (int j = 0; j < CH; j++) {
                const size_t lt2 = lt0 + tc + CH + j;
                ndb[j] = dlt[rowDX + (t0 + lt2)*1024];
                nxb[j] = xin[rowDX + (t0 + lt2)*1024];
                nbv[j] = bf2f(Bbf[rowBC + lt2*32768]);
                ncv[j] = bf2f(Cbf[rowBC + lt2*32768]);
            }
        }
        #pragma unroll
        for (int j = 0; j < CH; j++) {
            const float a = __expf(db[j] * Aes);
            h = a*h + bv[j]*xb[j];
            float p = cv[j]*h;
            p += __shfl_xor(p, 16, 32);
            p += __shfl_xor(p, 8, 32);
            p += __shfl_xor(p, 4, 32);
            p += __shfl_xor(p, 2, 32);
            p += __shfl_xor(p, 1, 32);
            if (s == 0) {
                const float y = p / (1.f + __expf(-p));  // SiLU
                Ybf[rowDX + (size_t)(t0 + lt0 + tc + j)*1024] = f2bf(y);
            }
        }
        if (more) {
            #pragma unroll
            for (int j = 0; j < CH; j++) { db[j]=ndb[j]; xb[j]=nxb[j]; bv[j]=nbv[j]; cv[j]=ncv[j]; }
        }
    }
}

// ---------------- launch ----------------
extern "C" void kernel_launch(void* const* d_in, const int* in_sizes, int n_in,
                              void* d_out, int out_size, void* d_ws, size_t ws_size,
                              hipStream_t stream) {
    const float* x     = (const float*)d_in[0];
    const float* Wx    = (const float*)d_in[1];
    const float* Wdt   = (const float*)d_in[2];
    const float* bdt   = (const float*)d_in[3];
    const float* A_log = (const float*)d_in[4];
    const float* WB    = (const float*)d_in[5];
    const float* WC    = (const float*)d_in[6];
    const float* Wout  = (const float*)d_in[7];

    // ---- workspace layout (fixed part = 99,876,864 B) ----
    char* ws = (char*)d_ws;
    unsigned short* Wbf    = (unsigned short*)(ws);                 // 69,206,016
    unsigned short* Xbf    = (unsigned short*)(ws + 69206016);      //  2,097,152
    unsigned short* Woutbf = (unsigned short*)(ws + 71303168);      //  1,048,576
    float*          xin    = (float*)        (ws + 72351744);       //  8,388,608
    float*          dlt    = (float*)        (ws + 80740352);       //  8,388,608
    unsigned short* Ybf    = (unsigned short*)(ws + 89128960);      //  4,194,304
    float*          hbuf   = (float*)        (ws + 93323264);       //    262,144
    float*          sc_h   = (float*)        (ws + 93585408);       //  2,097,152 (SEG<=8)
    float*          sc_a   = (float*)        (ws + 95682560);       //  2,097,152
    float*          sc_hin = (float*)        (ws + 97779712);       //  2,097,152
    unsigned short* Bbf    = (unsigned short*)(ws + 99876864);      // T*131072 B each
    const size_t fixedB = 99876864;

    int T = 128;
    const int cands[4] = {1024, 512, 256, 128};
    for (int ci = 0; ci < 4; ci++) {
        if (fixedB + (size_t)2 * cands[ci] * 131072 <= ws_size) { T = cands[ci]; break; }
    }
    unsigned short* Cbf = Bbf + (size_t)T * 65536;

    const int SEG = 8;
    const int Tg = T / SEG;

    cast_all<<<dim3(2048), dim3(256), 0, stream>>>(
        (const float4*)Wx, (const float4*)Wdt, (const float4*)WB, (const float4*)WC,
        (const float4*)x, (const float4*)Wout, Wbf, Xbf, Woutbf);

    const int NC = SEQLEN / T;
    for (int c = 0; c < NC; c++) {
        const int t0 = c * T;
        gemm_bt<0><<<dim3(NPROJ/128, 2*T/128), dim3(256), 0, stream>>>(
            Xbf, Wbf, DMODEL, NPROJ, t0, T, xin, dlt, Bbf, Cbf, bdt, nullptr);
        scan_seg1<<<dim3(256, SEG), dim3(256), 0, stream>>>(
            dlt, xin, Bbf, A_log, sc_h, sc_a, t0, T, SEG, Tg);
        scan_seg2<<<dim3(256), dim3(256), 0, stream>>>(
            sc_h, sc_a, sc_hin, hbuf, SEG, (c == 0) ? 1 : 0);
        scan_seg3<<<dim3(256, SEG), dim3(256), 0, stream>>>(
            dlt, xin, Bbf, Cbf, A_log, sc_hin, Ybf, t0, T, SEG, Tg);
    }

    gemm_bt<1><<<dim3(DMODEL/128, MROWS/128), dim3(256), 0, stream>>>(
        Ybf, Woutbf, DINNER, DMODEL, 0, MROWS, nullptr, nullptr, nullptr, nullptr, nullptr,
        (float*)d_out);
}

// Round 6
// 468.068 us; speedup vs baseline: 1.2774x; 1.2774x over previous
//
#include <hip/hip_runtime.h>

// ---------------- constants ----------------
#define BATCH   2
#define SEQLEN  1024
#define DMODEL  512
#define DSTATE  32
#define DINNER  1024
#define MROWS   (BATCH*SEQLEN)          // 2048
#define NPROJ   (2*DINNER + 2*DINNER*DSTATE)  // 67584

typedef short bf16x8 __attribute__((ext_vector_type(8)));
typedef float f32x4  __attribute__((ext_vector_type(4)));

__device__ __forceinline__ unsigned short f2bf(float f) {
    union { float f; unsigned u; } c; c.f = f;
    unsigned u = c.u;
    u += 0x7fffu + ((u >> 16) & 1u);   // RTNE
    return (unsigned short)(u >> 16);
}
__device__ __forceinline__ float bf2f(unsigned short h) {
    union { unsigned u; float f; } c; c.u = ((unsigned)h) << 16;
    return c.f;
}

// ---------------- cast fp32 -> bf16 (weights concat + x + Wout) ----------------
__global__ void cast_all(const float4* __restrict__ Wx, const float4* __restrict__ Wdt,
                         const float4* __restrict__ WB, const float4* __restrict__ WC,
                         const float4* __restrict__ x,  const float4* __restrict__ Wout,
                         unsigned short* __restrict__ Wbf,
                         unsigned short* __restrict__ Xbf,
                         unsigned short* __restrict__ Woutbf) {
    const long nWx = 131072, nWdt = 131072, nWB = 4194304, nWC = 4194304;
    const long nWall = nWx + nWdt + nWB + nWC;      // 8650752
    const long nX = 262144, nWo = 131072;
    const long total = nWall + nX + nWo;            // 9043968
    for (long u = (long)blockIdx.x * blockDim.x + threadIdx.x; u < total;
         u += (long)gridDim.x * blockDim.x) {
        float4 v; unsigned short* dst;
        if (u < nWall) {
            if (u < nWx)             v = Wx[u];
            else if (u < nWx+nWdt)   v = Wdt[u - nWx];
            else if (u < nWx+nWdt+nWB) v = WB[u - nWx - nWdt];
            else                     v = WC[u - nWx - nWdt - nWB];
            dst = Wbf + u*4;
        } else if (u < nWall + nX) {
            v = x[u - nWall];       dst = Xbf + (u - nWall)*4;
        } else {
            v = Wout[u - nWall - nX]; dst = Woutbf + (u - nWall - nX)*4;
        }
        ushort4 o; o.x = f2bf(v.x); o.y = f2bf(v.y); o.z = f2bf(v.z); o.w = f2bf(v.w);
        *(ushort4*)dst = o;
    }
}

// ---------------- bf16 MFMA GEMM: C[rows,N] = A[rows,K] * Bw[N,K]^T ----------------
// 128x128 tile, BK=32, 4 waves (2x2). XCD band swizzle; 2-deep double-buffer
// (32KB LDS -> 5 blocks/CU) with counted vmcnt(4); LDS bank-conflict-free via
// pre-swizzled GLOBAL source + same-involution swizzled ds_read.
// Swizzle: 16B slot' = slot ^ ((row>>1)&3).
template<int EPI>
__global__ __launch_bounds__(256)
void gemm_bt(const unsigned short* __restrict__ A, const unsigned short* __restrict__ Bw,
             int K, int N, int t0, int Tchunk,
             float* __restrict__ xin, float* __restrict__ dlt,
             unsigned short* __restrict__ Bout, unsigned short* __restrict__ Cout,
             const float* __restrict__ bdt, float* __restrict__ outf) {
    __shared__ unsigned short Asm[2][128*32];
    __shared__ unsigned short Bsm[2][128*32];
    const int tid  = threadIdx.x;
    const int w    = tid >> 6;
    const int lane = tid & 63;
    const int wm   = w >> 1, wn = w & 1;

    // ---- XCD band swizzle ----
    const int nx = gridDim.x, ny = gridDim.y;
    int ntile, rtile;
    if ((nx & 7) == 0) {
        const int lin = blockIdx.x + nx * blockIdx.y;
        const int xcd = lin & 7;
        const int sl  = lin >> 3;
        ntile = xcd * (nx >> 3) + sl / ny;
        rtile = sl % ny;
    } else {
        ntile = blockIdx.x; rtile = blockIdx.y;
    }

    const int rr0  = rtile * 128;                 // chunk-local row base of tile
    const int bb   = (rr0 >= Tchunk) ? 1 : 0;
    const int grow0 = bb * SEQLEN + t0 + (rr0 - bb * Tchunk);  // global row base
    const int n0   = ntile * 128;

    f32x4 acc[4][4] = {};

    const unsigned short* Ag = A  + (size_t)grow0 * K;
    const unsigned short* Bg = Bw + (size_t)n0 * K;

    const int c0 = w*64 + lane;       // LDS chunk ids (16B units)
    const int c1 = c0 + 256;
    const int r   = lane & 15;
    const int h16 = lane >> 4;

    // pre-swizzled global source offsets (shorts), add k0 per iteration
    const int rowc0 = c0 >> 2, rowc1 = c1 >> 2;
    const int subc0 = (c0 & 3) ^ ((c0 >> 3) & 3);
    const int subc1 = (c1 & 3) ^ ((c1 >> 3) & 3);
    const size_t srcA0 = (size_t)rowc0 * K + subc0 * 8;
    const size_t srcA1 = (size_t)rowc1 * K + subc1 * 8;

    const int nt = K >> 5;            // K/32 iterations

    #define STAGE(k0_, buf_)                                                              \
        do {                                                                              \
            __builtin_amdgcn_global_load_lds(                                             \
                (const __attribute__((address_space(1))) void*)(Ag + srcA0 + (k0_)),      \
                (__attribute__((address_space(3))) void*)(&Asm[(buf_)][w*512]), 16, 0, 0);\
            __builtin_amdgcn_global_load_lds(                                             \
                (const __attribute__((address_space(1))) void*)(Ag + srcA1 + (k0_)),      \
                (__attribute__((address_space(3))) void*)(&Asm[(buf_)][2048 + w*512]), 16, 0, 0); \
            __builtin_amdgcn_global_load_lds(                                             \
                (const __attribute__((address_space(1))) void*)(Bg + srcA0 + (k0_)),      \
                (__attribute__((address_space(3))) void*)(&Bsm[(buf_)][w*512]), 16, 0, 0);\
            __builtin_amdgcn_global_load_lds(                                             \
                (const __attribute__((address_space(1))) void*)(Bg + srcA1 + (k0_)),      \
                (__attribute__((address_space(3))) void*)(&Bsm[(buf_)][2048 + w*512]), 16, 0, 0); \
        } while (0)

    #define COMPUTE(buf_)                                                                 \
        do {                                                                              \
            bf16x8 af[4], bfr[4];                                                         \
            _Pragma("unroll")                                                             \
            for (int i = 0; i < 4; i++) {                                                 \
                const int Ra = wm*64 + i*16 + r;                                          \
                const int Rb = wn*64 + i*16 + r;                                          \
                af[i]  = *(const bf16x8*)(&Asm[(buf_)][Ra*32 + (h16 ^ ((Ra>>1)&3))*8]);   \
                bfr[i] = *(const bf16x8*)(&Bsm[(buf_)][Rb*32 + (h16 ^ ((Rb>>1)&3))*8]);   \
            }                                                                             \
            _Pragma("unroll")                                                             \
            for (int i = 0; i < 4; i++)                                                   \
                _Pragma("unroll")                                                         \
                for (int j = 0; j < 4; j++)                                               \
                    acc[i][j] = __builtin_amdgcn_mfma_f32_16x16x32_bf16(af[i], bfr[j], acc[i][j], 0, 0, 0); \
        } while (0)

    STAGE(0, 0);
    for (int it = 0; it < nt - 1; ++it) {
        const int cur = it & 1;
        STAGE((it + 1) * 32, cur ^ 1);
        asm volatile("s_waitcnt vmcnt(4)" ::: "memory");   // old 4 landed; new 4 in flight
        __builtin_amdgcn_s_barrier();
        COMPUTE(cur);
        asm volatile("" ::: "memory");
        __builtin_amdgcn_s_barrier();                      // protect buf cur before re-stage
        asm volatile("" ::: "memory");
    }
    asm volatile("s_waitcnt vmcnt(0)" ::: "memory");
    __builtin_amdgcn_s_barrier();
    COMPUTE((nt - 1) & 1);

    #undef STAGE
    #undef COMPUTE

    // epilogue: C/D layout col=lane&15, row=(lane>>4)*4+reg
    const int q = lane >> 4;
    #pragma unroll
    for (int i = 0; i < 4; i++) {
        #pragma unroll
        for (int j = 0; j < 4; j++) {
            const int lr0  = wm*64 + i*16 + q*4;   // local row within tile
            const int ncol = n0 + wn*64 + j*16 + r;
            #pragma unroll
            for (int t = 0; t < 4; t++) {
                const int lr = lr0 + t;
                const int mm = grow0 + lr;          // global row
                const int cr = rr0 + lr;            // chunk-local row
                const float v = acc[i][j][t];
                if (EPI == 0) {
                    if (ncol < 1024) {
                        xin[(size_t)mm*1024 + ncol] = v;
                    } else if (ncol < 2048) {
                        float z = v + bdt[ncol - 1024];
                        dlt[(size_t)mm*1024 + (ncol - 1024)] = (z > 20.f) ? z : log1pf(__expf(z));
                    } else if (ncol < 34816) {
                        Bout[(size_t)cr*32768 + (ncol - 2048)] = f2bf(v);
                    } else {
                        Cout[(size_t)cr*32768 + (ncol - 34816)] = f2bf(v);
                    }
                } else {
                    outf[(size_t)mm*N + ncol] = v;
                }
            }
        }
    }
}

// ================= segmented scan =================
// SC1: per (b,e) group and segment: local scan from h=0, record h_loc and
//      a_prod (32-dim each). grid: (256, SEG) blocks x 256 thr.
__global__ __launch_bounds__(256)
void scan_seg1(const float* __restrict__ dlt, const float* __restrict__ xin,
               const unsigned short* __restrict__ Bbf,
               const float* __restrict__ A_log,
               float* __restrict__ sc_h, float* __restrict__ sc_a,
               int t0, int Tchunk, int SEG, int Tg) {
    const int tid = threadIdx.x;
    const int g = tid >> 5;
    const int s = tid & 31;
    const int G = blockIdx.x * 8 + g;        // 0..2047 (b,e)
    const int seg = blockIdx.y;
    const int b = G >> 10, e = G & 1023;

    const float Aes = -__expf(A_log[e*32 + s]);
    float h = 0.f, ap = 1.f;

    const int lt0 = seg * Tg;                      // chunk-local start
    const size_t rowBC = (size_t)b*Tchunk*32768 + (size_t)e*32 + s;
    const size_t rowDX = (size_t)b*1024*1024 + e;

    const int CH = 8;
    float db[CH], xb[CH], bv[CH];
    #pragma unroll
    for (int j = 0; j < CH; j++) {
        db[j] = dlt[rowDX + (size_t)(t0 + lt0 + j)*1024];
        xb[j] = xin[rowDX + (size_t)(t0 + lt0 + j)*1024];
        bv[j] = bf2f(Bbf[rowBC + (size_t)(lt0 + j)*32768]);
    }
    for (int tc = 0; tc < Tg; tc += CH) {
        float ndb[CH], nxb[CH], nbv[CH];
        const bool more = (tc + CH) < Tg;
        if (more) {
            #pragma unroll
            for (int j = 0; j < CH; j++) {
                const size_t lt2 = lt0 + tc + CH + j;
                ndb[j] = dlt[rowDX + (t0 + lt2)*1024];
                nxb[j] = xin[rowDX + (t0 + lt2)*1024];
                nbv[j] = bf2f(Bbf[rowBC + lt2*32768]);
            }
        }
        #pragma unroll
        for (int j = 0; j < CH; j++) {
            const float a = __expf(db[j] * Aes);
            h = a*h + bv[j]*xb[j];
            ap *= a;
        }
        if (more) {
            #pragma unroll
            for (int j = 0; j < CH; j++) { db[j]=ndb[j]; xb[j]=nxb[j]; bv[j]=nbv[j]; }
        }
    }
    sc_h[((size_t)G*SEG + seg)*32 + s] = h;
    sc_a[((size_t)G*SEG + seg)*32 + s] = ap;
}

// SC2: compose segment boundaries sequentially (SEG steps). 65536 threads.
__global__ __launch_bounds__(256)
void scan_seg2(const float* __restrict__ sc_h, const float* __restrict__ sc_a,
               float* __restrict__ sc_hin, float* __restrict__ hbuf,
               int SEG, int first) {
    const int idx = blockIdx.x * 256 + threadIdx.x;   // 0..65535 = G*32+s
    float h = first ? 0.f : hbuf[idx];
    const int G = idx >> 5, s = idx & 31;
    for (int seg = 0; seg < SEG; seg++) {
        const size_t o = ((size_t)G*SEG + seg)*32 + s;
        sc_hin[o] = h;
        h = sc_h[o] + sc_a[o]*h;
    }
    hbuf[idx] = h;
}

// SC3: re-scan each segment with correct h_in; emit y (SiLU) as bf16.
// Batched-8 butterfly fold: 9 shuffles per 8 t (vs 40); the 8 SiLU+stores run
// on 8 parallel lanes. Fold mapping: lane s (s&3==0) ends with t_local = s>>2.
__global__ __launch_bounds__(256)
void scan_seg3(const float* __restrict__ dlt, const float* __restrict__ xin,
               const unsigned short* __restrict__ Bbf, const unsigned short* __restrict__ Cbf,
               const float* __restrict__ A_log, const float* __restrict__ sc_hin,
               unsigned short* __restrict__ Ybf,
               int t0, int Tchunk, int SEG, int Tg) {
    const int tid = threadIdx.x;
    const int g = tid >> 5;
    const int s = tid & 31;
    const int G = blockIdx.x * 8 + g;
    const int seg = blockIdx.y;
    const int b = G >> 10, e = G & 1023;

    const float Aes = -__expf(A_log[e*32 + s]);
    float h = sc_hin[((size_t)G*SEG + seg)*32 + s];

    const int lt0 = seg * Tg;
    const size_t rowBC = (size_t)b*Tchunk*32768 + (size_t)e*32 + s;
    const size_t rowDX = (size_t)b*1024*1024 + e;

    const int CH = 8;
    float db[CH], xb[CH], bv[CH], cv[CH];
    #pragma unroll
    for (int j = 0; j < CH; j++) {
        db[j] = dlt[rowDX + (size_t)(t0 + lt0 + j)*1024];
        xb[j] = xin[rowDX + (size_t)(t0 + lt0 + j)*1024];
        bv[j] = bf2f(Bbf[rowBC + (size_t)(lt0 + j)*32768]);
        cv[j] = bf2f(Cbf[rowBC + (size_t)(lt0 + j)*32768]);
    }
    for (int tc = 0; tc < Tg; tc += CH) {
        float ndb[CH], nxb[CH], nbv[CH], ncv[CH];
        const bool more = (tc + CH) < Tg;
        if (more) {
            #pragma unroll
            for (int j = 0; j < CH; j++) {
                const size_t lt2 = lt0 + tc + CH + j;
                ndb[j] = dlt[rowDX + (t0 + lt2)*1024];
                nxb[j] = xin[rowDX + (t0 + lt2)*1024];
                nbv[j] = bf2f(Bbf[rowBC + lt2*32768]);
                ncv[j] = bf2f(Cbf[rowBC + lt2*32768]);
            }
        }
        float p[CH];
        #pragma unroll
        for (int j = 0; j < CH; j++) {
            const float a = __expf(db[j] * Aes);
            h = a*h + bv[j]*xb[j];
            p[j] = cv[j]*h;
        }
        // ---- butterfly fold: reduce 8 t-values across 32 lanes ----
        // L1 mask16: keep half by s&16 (t-bit 2)
        #pragma unroll
        for (int i = 0; i < 4; i++) {
            float send = (s & 16) ? p[i] : p[i+4];
            float recv = __shfl_xor(send, 16, 32);
            p[i] = ((s & 16) ? p[i+4] : p[i]) + recv;
        }
        // L2 mask8 (t-bit 1)
        #pragma unroll
        for (int i = 0; i < 2; i++) {
            float send = (s & 8) ? p[i] : p[i+2];
            float recv = __shfl_xor(send, 8, 32);
            p[i] = ((s & 8) ? p[i+2] : p[i]) + recv;
        }
        // L3 mask4 (t-bit 0)
        {
            float send = (s & 4) ? p[0] : p[1];
            float recv = __shfl_xor(send, 4, 32);
            p[0] = ((s & 4) ? p[1] : p[0]) + recv;
        }
        // L4/L5: plain sums over remaining 4 lanes
        p[0] += __shfl_xor(p[0], 2, 32);
        p[0] += __shfl_xor(p[0], 1, 32);
        if ((s & 3) == 0) {
            const int tl = s >> 2;
            const float q = p[0];
            const float y = q * __builtin_amdgcn_rcpf(1.f + __expf(-q));  // SiLU
            Ybf[rowDX + (size_t)(t0 + lt0 + tc + tl)*1024] = f2bf(y);
        }
        if (more) {
            #pragma unroll
            for (int j = 0; j < CH; j++) { db[j]=ndb[j]; xb[j]=nxb[j]; bv[j]=nbv[j]; cv[j]=ncv[j]; }
        }
    }
}

// ---------------- launch ----------------
extern "C" void kernel_launch(void* const* d_in, const int* in_sizes, int n_in,
                              void* d_out, int out_size, void* d_ws, size_t ws_size,
                              hipStream_t stream) {
    const float* x     = (const float*)d_in[0];
    const float* Wx    = (const float*)d_in[1];
    const float* Wdt   = (const float*)d_in[2];
    const float* bdt   = (const float*)d_in[3];
    const float* A_log = (const float*)d_in[4];
    const float* WB    = (const float*)d_in[5];
    const float* WC    = (const float*)d_in[6];
    const float* Wout  = (const float*)d_in[7];

    // ---- workspace layout (fixed part = 99,876,864 B) ----
    char* ws = (char*)d_ws;
    unsigned short* Wbf    = (unsigned short*)(ws);                 // 69,206,016
    unsigned short* Xbf    = (unsigned short*)(ws + 69206016);      //  2,097,152
    unsigned short* Woutbf = (unsigned short*)(ws + 71303168);      //  1,048,576
    float*          xin    = (float*)        (ws + 72351744);       //  8,388,608
    float*          dlt    = (float*)        (ws + 80740352);       //  8,388,608
    unsigned short* Ybf    = (unsigned short*)(ws + 89128960);      //  4,194,304
    float*          hbuf   = (float*)        (ws + 93323264);       //    262,144
    float*          sc_h   = (float*)        (ws + 93585408);       //  2,097,152 (SEG<=8)
    float*          sc_a   = (float*)        (ws + 95682560);       //  2,097,152
    float*          sc_hin = (float*)        (ws + 97779712);       //  2,097,152
    unsigned short* Bbf    = (unsigned short*)(ws + 99876864);      // T*131072 B each
    const size_t fixedB = 99876864;

    int T = 128;
    const int cands[4] = {1024, 512, 256, 128};
    for (int ci = 0; ci < 4; ci++) {
        if (fixedB + (size_t)2 * cands[ci] * 131072 <= ws_size) { T = cands[ci]; break; }
    }
    unsigned short* Cbf = Bbf + (size_t)T * 65536;

    const int SEG = 8;
    const int Tg = T / SEG;

    cast_all<<<dim3(2048), dim3(256), 0, stream>>>(
        (const float4*)Wx, (const float4*)Wdt, (const float4*)WB, (const float4*)WC,
        (const float4*)x, (const float4*)Wout, Wbf, Xbf, Woutbf);

    const int NC = SEQLEN / T;
    for (int c = 0; c < NC; c++) {
        const int t0 = c * T;
        gemm_bt<0><<<dim3(NPROJ/128, 2*T/128), dim3(256), 0, stream>>>(
            Xbf, Wbf, DMODEL, NPROJ, t0, T, xin, dlt, Bbf, Cbf, bdt, nullptr);
        scan_seg1<<<dim3(256, SEG), dim3(256), 0, stream>>>(
            dlt, xin, Bbf, A_log, sc_h, sc_a, t0, T, SEG, Tg);
        scan_seg2<<<dim3(256), dim3(256), 0, stream>>>(
            sc_h, sc_a, sc_hin, hbuf, SEG, (c == 0) ? 1 : 0);
        scan_seg3<<<dim3(256, SEG), dim3(256), 0, stream>>>(
            dlt, xin, Bbf, Cbf, A_log, sc_hin, Ybf, t0, T, SEG, Tg);
    }

    gemm_bt<1><<<dim3(DMODEL/128, MROWS/128), dim3(256), 0, stream>>>(
        Ybf, Woutbf, DINNER, DMODEL, 0, MROWS, nullptr, nullptr, nullptr, nullptr, nullptr,
        (float*)d_out);
}

// Round 7
// 409.316 us; speedup vs baseline: 1.4608x; 1.1435x over previous
//
#include <hip/hip_runtime.h>

// ---------------- constants ----------------
#define BATCH   2
#define SEQLEN  1024
#define DMODEL  512
#define DSTATE  32
#define DINNER  1024
#define MROWS   (BATCH*SEQLEN)          // 2048
#define NPROJ   (2*DINNER + 2*DINNER*DSTATE)  // 67584

typedef short bf16x8 __attribute__((ext_vector_type(8)));
typedef float f32x4  __attribute__((ext_vector_type(4)));

__device__ __forceinline__ unsigned short f2bf(float f) {
    union { float f; unsigned u; } c; c.f = f;
    unsigned u = c.u;
    u += 0x7fffu + ((u >> 16) & 1u);   // RTNE
    return (unsigned short)(u >> 16);
}
__device__ __forceinline__ float bf2f(unsigned short h) {
    union { unsigned u; float f; } c; c.u = ((unsigned)h) << 16;
    return c.f;
}

// ---------------- cast fp32 -> bf16 (weights concat + x + Wout) ----------------
__global__ void cast_all(const float4* __restrict__ Wx, const float4* __restrict__ Wdt,
                         const float4* __restrict__ WB, const float4* __restrict__ WC,
                         const float4* __restrict__ x,  const float4* __restrict__ Wout,
                         unsigned short* __restrict__ Wbf,
                         unsigned short* __restrict__ Xbf,
                         unsigned short* __restrict__ Woutbf) {
    const long nWx = 131072, nWdt = 131072, nWB = 4194304, nWC = 4194304;
    const long nWall = nWx + nWdt + nWB + nWC;      // 8650752
    const long nX = 262144, nWo = 131072;
    const long total = nWall + nX + nWo;            // 9043968
    for (long u = (long)blockIdx.x * blockDim.x + threadIdx.x; u < total;
         u += (long)gridDim.x * blockDim.x) {
        float4 v; unsigned short* dst;
        if (u < nWall) {
            if (u < nWx)             v = Wx[u];
            else if (u < nWx+nWdt)   v = Wdt[u - nWx];
            else if (u < nWx+nWdt+nWB) v = WB[u - nWx - nWdt];
            else                     v = WC[u - nWx - nWdt - nWB];
            dst = Wbf + u*4;
        } else if (u < nWall + nX) {
            v = x[u - nWall];       dst = Xbf + (u - nWall)*4;
        } else {
            v = Wout[u - nWall - nX]; dst = Woutbf + (u - nWall - nX)*4;
        }
        ushort4 o; o.x = f2bf(v.x); o.y = f2bf(v.y); o.z = f2bf(v.z); o.w = f2bf(v.w);
        *(ushort4*)dst = o;
    }
}

// ---------------- bf16 MFMA GEMM: C[rows,N] = A[rows,K] * Bw[N,K]^T ----------------
// 128x128 tile, BK=32, 4 waves (2x2). XCD band swizzle; 2-deep double-buffer
// with counted vmcnt(4); bank-conflict-free LDS via pre-swizzled global source.
// EPI 0 stores to TIME-BLOCKED layouts (tblk = t/8, tin = t%8):
//   xin/dlt : [b][tblk][e][tin]      (float, 8192 per tblk)
//   B/C     : [b][tblk][e*32+s][tin] (bf16, 262144 per tblk)
// so each fragment's 4 t-values become one float4/short4 store.
template<int EPI>
__global__ __launch_bounds__(256)
void gemm_bt(const unsigned short* __restrict__ A, const unsigned short* __restrict__ Bw,
             int K, int N, int t0, int Tchunk,
             float* __restrict__ xin, float* __restrict__ dlt,
             unsigned short* __restrict__ Bout, unsigned short* __restrict__ Cout,
             const float* __restrict__ bdt, float* __restrict__ outf) {
    __shared__ unsigned short Asm[2][128*32];
    __shared__ unsigned short Bsm[2][128*32];
    const int tid  = threadIdx.x;
    const int w    = tid >> 6;
    const int lane = tid & 63;
    const int wm   = w >> 1, wn = w & 1;

    // ---- XCD band swizzle ----
    const int nx = gridDim.x, ny = gridDim.y;
    int ntile, rtile;
    if ((nx & 7) == 0) {
        const int lin = blockIdx.x + nx * blockIdx.y;
        const int xcd = lin & 7;
        const int sl  = lin >> 3;
        ntile = xcd * (nx >> 3) + sl / ny;
        rtile = sl % ny;
    } else {
        ntile = blockIdx.x; rtile = blockIdx.y;
    }

    const int rr0  = rtile * 128;                 // chunk-local row base of tile
    const int bb   = (rr0 >= Tchunk) ? 1 : 0;
    const int grow0 = bb * SEQLEN + t0 + (rr0 - bb * Tchunk);  // global row base
    const int n0   = ntile * 128;

    f32x4 acc[4][4] = {};

    const unsigned short* Ag = A  + (size_t)grow0 * K;
    const unsigned short* Bg = Bw + (size_t)n0 * K;

    const int c0 = w*64 + lane;       // LDS chunk ids (16B units)
    const int c1 = c0 + 256;
    const int r   = lane & 15;
    const int h16 = lane >> 4;

    // pre-swizzled global source offsets (shorts), add k0 per iteration
    const int rowc0 = c0 >> 2, rowc1 = c1 >> 2;
    const int subc0 = (c0 & 3) ^ ((c0 >> 3) & 3);
    const int subc1 = (c1 & 3) ^ ((c1 >> 3) & 3);
    const size_t srcA0 = (size_t)rowc0 * K + subc0 * 8;
    const size_t srcA1 = (size_t)rowc1 * K + subc1 * 8;

    const int nt = K >> 5;            // K/32 iterations

    #define STAGE(k0_, buf_)                                                              \
        do {                                                                              \
            __builtin_amdgcn_global_load_lds(                                             \
                (const __attribute__((address_space(1))) void*)(Ag + srcA0 + (k0_)),      \
                (__attribute__((address_space(3))) void*)(&Asm[(buf_)][w*512]), 16, 0, 0);\
            __builtin_amdgcn_global_load_lds(                                             \
                (const __attribute__((address_space(1))) void*)(Ag + srcA1 + (k0_)),      \
                (__attribute__((address_space(3))) void*)(&Asm[(buf_)][2048 + w*512]), 16, 0, 0); \
            __builtin_amdgcn_global_load_lds(                                             \
                (const __attribute__((address_space(1))) void*)(Bg + srcA0 + (k0_)),      \
                (__attribute__((address_space(3))) void*)(&Bsm[(buf_)][w*512]), 16, 0, 0);\
            __builtin_amdgcn_global_load_lds(                                             \
                (const __attribute__((address_space(1))) void*)(Bg + srcA1 + (k0_)),      \
                (__attribute__((address_space(3))) void*)(&Bsm[(buf_)][2048 + w*512]), 16, 0, 0); \
        } while (0)

    #define COMPUTE(buf_)                                                                 \
        do {                                                                              \
            bf16x8 af[4], bfr[4];                                                         \
            _Pragma("unroll")                                                             \
            for (int i = 0; i < 4; i++) {                                                 \
                const int Ra = wm*64 + i*16 + r;                                          \
                const int Rb = wn*64 + i*16 + r;                                          \
                af[i]  = *(const bf16x8*)(&Asm[(buf_)][Ra*32 + (h16 ^ ((Ra>>1)&3))*8]);   \
                bfr[i] = *(const bf16x8*)(&Bsm[(buf_)][Rb*32 + (h16 ^ ((Rb>>1)&3))*8]);   \
            }                                                                             \
            _Pragma("unroll")                                                             \
            for (int i = 0; i < 4; i++)                                                   \
                _Pragma("unroll")                                                         \
                for (int j = 0; j < 4; j++)                                               \
                    acc[i][j] = __builtin_amdgcn_mfma_f32_16x16x32_bf16(af[i], bfr[j], acc[i][j], 0, 0, 0); \
        } while (0)

    STAGE(0, 0);
    for (int it = 0; it < nt - 1; ++it) {
        const int cur = it & 1;
        STAGE((it + 1) * 32, cur ^ 1);
        asm volatile("s_waitcnt vmcnt(4)" ::: "memory");   // old 4 landed; new 4 in flight
        __builtin_amdgcn_s_barrier();
        COMPUTE(cur);
        asm volatile("" ::: "memory");
        __builtin_amdgcn_s_barrier();                      // protect buf cur before re-stage
        asm volatile("" ::: "memory");
    }
    asm volatile("s_waitcnt vmcnt(0)" ::: "memory");
    __builtin_amdgcn_s_barrier();
    COMPUTE((nt - 1) & 1);

    #undef STAGE
    #undef COMPUTE

    // epilogue: C/D layout col=lane&15, row=(lane>>4)*4+reg
    const int q = lane >> 4;
    #pragma unroll
    for (int i = 0; i < 4; i++) {
        const int lr0 = wm*64 + i*16 + q*4;      // local row base (4 consecutive rows)
        #pragma unroll
        for (int j = 0; j < 4; j++) {
            const int ncol = n0 + wn*64 + j*16 + r;
            if (EPI == 0) {
                const int cr   = rr0 + lr0;              // chunk-local row
                const int lt   = cr - bb*Tchunk;         // chunk-local t (of first of 4)
                const size_t tb = (size_t)(lt >> 3);
                const int tin  = lt & 7;                 // 0 or 4
                if (ncol < 1024) {
                    float4 o = {acc[i][j][0], acc[i][j][1], acc[i][j][2], acc[i][j][3]};
                    *(float4*)(xin + ((size_t)bb*(SEQLEN/8) + (t0>>3) + tb)*8192 + ncol*8 + tin) = o;
                } else if (ncol < 2048) {
                    const float bias = bdt[ncol - 1024];
                    float4 o;
                    {   float z0 = acc[i][j][0] + bias; o.x = (z0 > 20.f) ? z0 : log1pf(__expf(z0));
                        float z1 = acc[i][j][1] + bias; o.y = (z1 > 20.f) ? z1 : log1pf(__expf(z1));
                        float z2 = acc[i][j][2] + bias; o.z = (z2 > 20.f) ? z2 : log1pf(__expf(z2));
                        float z3 = acc[i][j][3] + bias; o.w = (z3 > 20.f) ? z3 : log1pf(__expf(z3)); }
                    *(float4*)(dlt + ((size_t)bb*(SEQLEN/8) + (t0>>3) + tb)*8192 + (ncol-1024)*8 + tin) = o;
                } else if (ncol < 34816) {
                    const int cb = ncol - 2048;
                    short4 o;
                    o.x = (short)f2bf(acc[i][j][0]); o.y = (short)f2bf(acc[i][j][1]);
                    o.z = (short)f2bf(acc[i][j][2]); o.w = (short)f2bf(acc[i][j][3]);
                    *(short4*)(Bout + ((size_t)bb*(Tchunk>>3) + tb)*262144 + (size_t)cb*8 + tin) = o;
                } else {
                    const int cc = ncol - 34816;
                    short4 o;
                    o.x = (short)f2bf(acc[i][j][0]); o.y = (short)f2bf(acc[i][j][1]);
                    o.z = (short)f2bf(acc[i][j][2]); o.w = (short)f2bf(acc[i][j][3]);
                    *(short4*)(Cout + ((size_t)bb*(Tchunk>>3) + tb)*262144 + (size_t)cc*8 + tin) = o;
                }
            } else {
                #pragma unroll
                for (int t = 0; t < 4; t++)
                    outf[(size_t)(grow0 + lr0 + t)*N + ncol] = acc[i][j][t];
            }
        }
    }
}

// ================= segmented scan (time-blocked layouts) =================
// SC1: per (b,e) group and segment: local scan from h=0, record h_loc, a_prod.
__global__ __launch_bounds__(256)
void scan_seg1(const float* __restrict__ dlt, const float* __restrict__ xin,
               const unsigned short* __restrict__ Bbf,
               const float* __restrict__ A_log,
               float* __restrict__ sc_h, float* __restrict__ sc_a,
               int t0, int Tchunk, int SEG, int Tg) {
    const int tid = threadIdx.x;
    const int g = tid >> 5, s = tid & 31;
    const int G = blockIdx.x * 8 + g;        // 0..2047 (b,e)
    const int seg = blockIdx.y;
    const int b = G >> 10, e = G & 1023;

    const float Aes = -__expf(A_log[e*32 + s]);
    float h = 0.f, ap = 1.f;

    const int NT  = Tg >> 3;
    const int gt0 = (t0 + seg*Tg) >> 3;      // global tblk base for dlt/xin
    const int ct0 = (seg*Tg) >> 3;           // chunk tblk base for B
    const float* dxp = dlt + ((size_t)b*(SEQLEN/8) + gt0)*8192 + e*8;
    const float* xxp = xin + ((size_t)b*(SEQLEN/8) + gt0)*8192 + e*8;
    const unsigned short* bp = Bbf + ((size_t)b*(Tchunk>>3) + ct0)*262144 + (size_t)(e*32+s)*8;

    float4 d0 = *(const float4*)dxp, d1 = *(const float4*)(dxp+4);
    float4 x0 = *(const float4*)xxp, x1 = *(const float4*)(xxp+4);
    bf16x8 bv = *(const bf16x8*)bp;

    for (int k = 0; k < NT; ++k) {
        float4 nd0, nd1, nx0, nx1; bf16x8 nbv;
        if (k + 1 < NT) {
            const float* p1 = dxp + (size_t)(k+1)*8192;
            nd0 = *(const float4*)p1; nd1 = *(const float4*)(p1+4);
            const float* p2 = xxp + (size_t)(k+1)*8192;
            nx0 = *(const float4*)p2; nx1 = *(const float4*)(p2+4);
            nbv = *(const bf16x8*)(bp + (size_t)(k+1)*262144);
        }
        const float db[8] = {d0.x,d0.y,d0.z,d0.w,d1.x,d1.y,d1.z,d1.w};
        const float xb[8] = {x0.x,x0.y,x0.z,x0.w,x1.x,x1.y,x1.z,x1.w};
        #pragma unroll
        for (int j = 0; j < 8; j++) {
            const float a = __expf(db[j] * Aes);
            h = a*h + bf2f((unsigned short)bv[j])*xb[j];
            ap *= a;
        }
        if (k + 1 < NT) { d0=nd0; d1=nd1; x0=nx0; x1=nx1; bv=nbv; }
    }
    sc_h[((size_t)G*SEG + seg)*32 + s] = h;
    sc_a[((size_t)G*SEG + seg)*32 + s] = ap;
}

// SC2: compose segment boundaries sequentially (SEG steps). 65536 threads.
__global__ __launch_bounds__(256)
void scan_seg2(const float* __restrict__ sc_h, const float* __restrict__ sc_a,
               float* __restrict__ sc_hin, float* __restrict__ hbuf,
               int SEG, int first) {
    const int idx = blockIdx.x * 256 + threadIdx.x;   // 0..65535 = G*32+s
    float h = first ? 0.f : hbuf[idx];
    const int G = idx >> 5, s = idx & 31;
    for (int seg = 0; seg < SEG; seg++) {
        const size_t o = ((size_t)G*SEG + seg)*32 + s;
        sc_hin[o] = h;
        h = sc_h[o] + sc_a[o]*h;
    }
    hbuf[idx] = h;
}

// SC3: re-scan each segment with correct h_in; butterfly-fold 8 t per round;
// emit y (SiLU) as bf16 into row-major [global row][e] for the output GEMM.
__global__ __launch_bounds__(256)
void scan_seg3(const float* __restrict__ dlt, const float* __restrict__ xin,
               const unsigned short* __restrict__ Bbf, const unsigned short* __restrict__ Cbf,
               const float* __restrict__ A_log, const float* __restrict__ sc_hin,
               unsigned short* __restrict__ Ybf,
               int t0, int Tchunk, int SEG, int Tg) {
    const int tid = threadIdx.x;
    const int g = tid >> 5, s = tid & 31;
    const int G = blockIdx.x * 8 + g;
    const int seg = blockIdx.y;
    const int b = G >> 10, e = G & 1023;

    const float Aes = -__expf(A_log[e*32 + s]);
    float h = sc_hin[((size_t)G*SEG + seg)*32 + s];

    const int NT  = Tg >> 3;
    const int gt0 = (t0 + seg*Tg) >> 3;
    const int ct0 = (seg*Tg) >> 3;
    const float* dxp = dlt + ((size_t)b*(SEQLEN/8) + gt0)*8192 + e*8;
    const float* xxp = xin + ((size_t)b*(SEQLEN/8) + gt0)*8192 + e*8;
    const unsigned short* bp = Bbf + ((size_t)b*(Tchunk>>3) + ct0)*262144 + (size_t)(e*32+s)*8;
    const unsigned short* cp = Cbf + ((size_t)b*(Tchunk>>3) + ct0)*262144 + (size_t)(e*32+s)*8;
    const int tbase = t0 + seg*Tg;

    float4 d0 = *(const float4*)dxp, d1 = *(const float4*)(dxp+4);
    float4 x0 = *(const float4*)xxp, x1 = *(const float4*)(xxp+4);
    bf16x8 bv = *(const bf16x8*)bp, cv = *(const bf16x8*)cp;

    for (int k = 0; k < NT; ++k) {
        float4 nd0, nd1, nx0, nx1; bf16x8 nbv, ncv;
        if (k + 1 < NT) {
            const float* p1 = dxp + (size_t)(k+1)*8192;
            nd0 = *(const float4*)p1; nd1 = *(const float4*)(p1+4);
            const float* p2 = xxp + (size_t)(k+1)*8192;
            nx0 = *(const float4*)p2; nx1 = *(const float4*)(p2+4);
            nbv = *(const bf16x8*)(bp + (size_t)(k+1)*262144);
            ncv = *(const bf16x8*)(cp + (size_t)(k+1)*262144);
        }
        const float db[8] = {d0.x,d0.y,d0.z,d0.w,d1.x,d1.y,d1.z,d1.w};
        const float xb[8] = {x0.x,x0.y,x0.z,x0.w,x1.x,x1.y,x1.z,x1.w};
        float p[8];
        #pragma unroll
        for (int j = 0; j < 8; j++) {
            const float a = __expf(db[j] * Aes);
            h = a*h + bf2f((unsigned short)bv[j])*xb[j];
            p[j] = bf2f((unsigned short)cv[j])*h;
        }
        // ---- butterfly fold: reduce 8 t-values across 32 lanes ----
        #pragma unroll
        for (int i = 0; i < 4; i++) {
            float send = (s & 16) ? p[i] : p[i+4];
            float recv = __shfl_xor(send, 16, 32);
            p[i] = ((s & 16) ? p[i+4] : p[i]) + recv;
        }
        #pragma unroll
        for (int i = 0; i < 2; i++) {
            float send = (s & 8) ? p[i] : p[i+2];
            float recv = __shfl_xor(send, 8, 32);
            p[i] = ((s & 8) ? p[i+2] : p[i]) + recv;
        }
        {
            float send = (s & 4) ? p[0] : p[1];
            float recv = __shfl_xor(send, 4, 32);
            p[0] = ((s & 4) ? p[1] : p[0]) + recv;
        }
        p[0] += __shfl_xor(p[0], 2, 32);
        p[0] += __shfl_xor(p[0], 1, 32);
        if ((s & 3) == 0) {
            const int tl = s >> 2;
            const float qv = p[0];
            const float y = qv * __builtin_amdgcn_rcpf(1.f + __expf(-qv));  // SiLU
            Ybf[(size_t)b*1048576 + e + (size_t)(tbase + k*8 + tl)*1024] = f2bf(y);
        }
        if (k + 1 < NT) { d0=nd0; d1=nd1; x0=nx0; x1=nx1; bv=nbv; cv=ncv; }
    }
}

// ---------------- launch ----------------
extern "C" void kernel_launch(void* const* d_in, const int* in_sizes, int n_in,
                              void* d_out, int out_size, void* d_ws, size_t ws_size,
                              hipStream_t stream) {
    const float* x     = (const float*)d_in[0];
    const float* Wx    = (const float*)d_in[1];
    const float* Wdt   = (const float*)d_in[2];
    const float* bdt   = (const float*)d_in[3];
    const float* A_log = (const float*)d_in[4];
    const float* WB    = (const float*)d_in[5];
    const float* WC    = (const float*)d_in[6];
    const float* Wout  = (const float*)d_in[7];

    // ---- workspace layout (fixed part = 99,876,864 B) ----
    char* ws = (char*)d_ws;
    unsigned short* Wbf    = (unsigned short*)(ws);                 // 69,206,016
    unsigned short* Xbf    = (unsigned short*)(ws + 69206016);      //  2,097,152
    unsigned short* Woutbf = (unsigned short*)(ws + 71303168);      //  1,048,576
    float*          xin    = (float*)        (ws + 72351744);       //  8,388,608
    float*          dlt    = (float*)        (ws + 80740352);       //  8,388,608
    unsigned short* Ybf    = (unsigned short*)(ws + 89128960);      //  4,194,304
    float*          hbuf   = (float*)        (ws + 93323264);       //    262,144
    float*          sc_h   = (float*)        (ws + 93585408);       //  2,097,152 (SEG<=8)
    float*          sc_a   = (float*)        (ws + 95682560);       //  2,097,152
    float*          sc_hin = (float*)        (ws + 97779712);       //  2,097,152
    unsigned short* Bbf    = (unsigned short*)(ws + 99876864);      // T*131072 B each
    const size_t fixedB = 99876864;

    int T = 128;
    const int cands[4] = {1024, 512, 256, 128};
    for (int ci = 0; ci < 4; ci++) {
        if (fixedB + (size_t)2 * cands[ci] * 131072 <= ws_size) { T = cands[ci]; break; }
    }
    unsigned short* Cbf = Bbf + (size_t)T * 65536;

    const int SEG = 8;
    const int Tg = T / SEG;

    cast_all<<<dim3(2048), dim3(256), 0, stream>>>(
        (const float4*)Wx, (const float4*)Wdt, (const float4*)WB, (const float4*)WC,
        (const float4*)x, (const float4*)Wout, Wbf, Xbf, Woutbf);

    const int NC = SEQLEN / T;
    for (int c = 0; c < NC; c++) {
        const int t0 = c * T;
        gemm_bt<0><<<dim3(NPROJ/128, 2*T/128), dim3(256), 0, stream>>>(
            Xbf, Wbf, DMODEL, NPROJ, t0, T, xin, dlt, Bbf, Cbf, bdt, nullptr);
        scan_seg1<<<dim3(256, SEG), dim3(256), 0, stream>>>(
            dlt, xin, Bbf, A_log, sc_h, sc_a, t0, T, SEG, Tg);
        scan_seg2<<<dim3(256), dim3(256), 0, stream>>>(
            sc_h, sc_a, sc_hin, hbuf, SEG, (c == 0) ? 1 : 0);
        scan_seg3<<<dim3(256, SEG), dim3(256), 0, stream>>>(
            dlt, xin, Bbf, Cbf, A_log, sc_hin, Ybf, t0, T, SEG, Tg);
    }

    gemm_bt<1><<<dim3(DMODEL/128, MROWS/128), dim3(256), 0, stream>>>(
        Ybf, Woutbf, DINNER, DMODEL, 0, MROWS, nullptr, nullptr, nullptr, nullptr, nullptr,
        (float*)d_out);
}